// Round 10
// baseline (190.999 us; speedup 1.0000x reference)
//
#include <hip/hip_runtime.h>
#include <hip/hip_bf16.h>
#include <math.h>

// B=2, S=2048, D=1024, H=16, HD=64, AD=128, M=B*S=4096
typedef __attribute__((ext_vector_type(8))) short short8;
typedef __attribute__((ext_vector_type(4))) float f32x4;

#define MFMA16(a,b,c) __builtin_amdgcn_mfma_f32_16x16x32_bf16((a),(b),(c),0,0,0)

__device__ __forceinline__ unsigned short f2bf(float f){
    union { __hip_bfloat16 b; unsigned short u; } cv;
    cv.b = __float2bfloat16(f);
    return cv.u;
}
__device__ __forceinline__ unsigned pk_bf16(float a, float b){
    unsigned r;
    asm("v_cvt_pk_bf16_f32 %0, %1, %2" : "=v"(r) : "v"(a), "v"(b));
    return r;
}
// 2^x via v_exp_f32 (gfx950 hardware exp2)
__device__ __forceinline__ float ex2(float x){
    return __builtin_amdgcn_exp2f(x);
}

#define GLD_LDS16(g, s) \
    __builtin_amdgcn_global_load_lds((const __attribute__((address_space(1))) void*)(g), \
                                     (__attribute__((address_space(3))) void*)(s), 16, 0, 0)

// 0.125 (1/sqrt(HD)) * log2(e) folded into Wq/bq -> softmax uses exp2
#define QSCALE 0.18033688011112042f
#define DEFER_THR 11.0f

// ---------------------------------------------------------------------------
// fp32 -> bf16 batched conversion (9 tensors) with per-job scale
// ---------------------------------------------------------------------------
struct CvtJobs {
    const float* src[9];
    unsigned short* dst[9];
    float scale[9];
    int n[9];
};

__global__ __launch_bounds__(256)
void convert_kernel(CvtJobs j, long long total4) {
    long long i4 = (long long)blockIdx.x * blockDim.x + threadIdx.x;
    if (i4 >= total4) return;
    long long rem = i4 * 4;
    int job = 0;
    while (job < 9 && rem >= j.n[job]) { rem -= j.n[job]; ++job; }
    if (job >= 9) return;
    const float sc = j.scale[job];
    const float4 v = *(const float4*)(j.src[job] + rem);
    ushort4 o;
    o.x = f2bf(v.x * sc); o.y = f2bf(v.y * sc);
    o.z = f2bf(v.z * sc); o.w = f2bf(v.w * sc);
    *(ushort4*)(j.dst[job] + rem) = o;
}

// ---------------------------------------------------------------------------
// Shared 128x128 GEMM main loop (m97 structure + conflict-free XOR swizzle).
// ---------------------------------------------------------------------------
#define GEMM128_LOOP(Aptr, Bptr)                                                     \
    f32x4 acc[4][4] = {};                                                            \
    for (int k0 = 0; k0 < K; k0 += 32) {                                             \
        __syncthreads();                                                             \
        _Pragma("unroll")                                                            \
        for (int c = 0; c < 2; ++c) {                                                \
            const int id = c * 256 + tid;                                            \
            const int row = id >> 2, u = id & 3;                                     \
            const int su = u ^ ((row >> 1) & 3);                                     \
            GLD_LDS16((const char*)(Aptr) + ((size_t)(m0 + row) * K + k0) * 2 + su * 16, \
                      (char*)As + (c * 256 + w * 64) * 16);                          \
            GLD_LDS16((const char*)(Bptr) + ((size_t)(n0 + row) * K + k0) * 2 + su * 16, \
                      (char*)Bs + (c * 256 + w * 64) * 16);                          \
        }                                                                            \
        __syncthreads();                                                             \
        short8 af[4], bfr[4];                                                        \
        _Pragma("unroll")                                                            \
        for (int i = 0; i < 4; ++i)                                                  \
            af[i] = *(const short8*)((const char*)As + (wr * 64 + i * 16 + lr) * 64 + ru * 16); \
        _Pragma("unroll")                                                            \
        for (int jj = 0; jj < 4; ++jj)                                               \
            bfr[jj] = *(const short8*)((const char*)Bs + (wc * 64 + jj * 16 + lr) * 64 + ru * 16); \
        _Pragma("unroll")                                                            \
        for (int i = 0; i < 4; ++i)                                                  \
            _Pragma("unroll")                                                        \
            for (int jj = 0; jj < 4; ++jj)                                           \
                acc[i][jj] = MFMA16(af[i], bfr[jj], acc[i][jj]);                     \
    }

// ---------------------------------------------------------------------------
// Fused QKV projection. grid (M/128, D/128, 3).
// ---------------------------------------------------------------------------
struct QKVArgs {
    const unsigned short* A[3];
    const unsigned short* W[3];
    const float* bias[3];
    float bscale[3];
    unsigned short* out[3];
};

__global__ __launch_bounds__(256)
void gemm_qkv(QKVArgs ar, int M, int N, int K)
{
    __shared__ unsigned short As[128 * 32];
    __shared__ unsigned short Bs[128 * 32];

    const int z = blockIdx.z;
    const unsigned short* A = ar.A[z];
    const unsigned short* W = ar.W[z];
    const int tid = threadIdx.x;
    const int w = tid >> 6, l = tid & 63;
    const int lr = l & 15, lg = l >> 4;
    const int wr = w >> 1, wc = w & 1;
    const int m0 = blockIdx.x * 128, n0 = blockIdx.y * 128;
    const int ru = lg ^ ((lr >> 1) & 3);

    GEMM128_LOOP(A, W)

    const float* bias = ar.bias[z];
    const float bsc = ar.bscale[z];
    unsigned short* out = ar.out[z];
    #pragma unroll
    for (int i = 0; i < 4; ++i)
        #pragma unroll
        for (int jj = 0; jj < 4; ++jj)
            #pragma unroll
            for (int r = 0; r < 4; ++r) {
                const int row = m0 + wr * 64 + i * 16 + lg * 4 + r;
                const int col = n0 + wc * 64 + jj * 16 + lr;
                const float c = acc[i][jj][r] + bias[col] * bsc;
                const int b = row >> 11, s = row & 2047, h = col >> 6, hd = col & 63;
                if (z < 2)
                    out[((((size_t)(b * 16 + h)) * 2048 + s) << 6) + hd] = f2bf(c);
                else
                    out[((((size_t)(b * 16 + h)) * 64 + hd) << 11) + s] = f2bf(c);
            }
}

// ---------------------------------------------------------------------------
// Generic 128x128 GEMM. MODE 2: fp32 out0 + bf16 out1 (O-proj).
// MODE 4: + fp32 residual(out1) -> fp32 out0 (adapter up).
// ---------------------------------------------------------------------------
template<int MODE>
__global__ __launch_bounds__(256)
void gemm_bf16(const unsigned short* __restrict__ A,
               const unsigned short* __restrict__ Wt,
               const float* __restrict__ bias,
               void* __restrict__ out0,
               void* __restrict__ out1,
               int M, int N, int K)
{
    __shared__ unsigned short As[128 * 32];
    __shared__ unsigned short Bs[128 * 32];

    const int tid = threadIdx.x;
    const int w = tid >> 6, l = tid & 63;
    const int lr = l & 15, lg = l >> 4;
    const int wr = w >> 1, wc = w & 1;
    const int m0 = blockIdx.x * 128, n0 = blockIdx.y * 128;
    const int ru = lg ^ ((lr >> 1) & 3);

    GEMM128_LOOP(A, Wt)

    #pragma unroll
    for (int i = 0; i < 4; ++i)
        #pragma unroll
        for (int jj = 0; jj < 4; ++jj)
            #pragma unroll
            for (int r = 0; r < 4; ++r) {
                const int row = m0 + wr * 64 + i * 16 + lg * 4 + r;
                const int col = n0 + wc * 64 + jj * 16 + lr;
                const float c = acc[i][jj][r] + bias[col];
                if (MODE == 2) {
                    ((float*)out0)[(size_t)row * N + col] = c;
                    ((unsigned short*)out1)[(size_t)row * N + col] = f2bf(c);
                } else {
                    ((float*)out0)[(size_t)row * N + col] =
                        c + ((const float*)out1)[(size_t)row * N + col];
                }
            }
}

// ---------------------------------------------------------------------------
// 64x64-tile GEMM + exact GELU (adapter down, N=128)
// ---------------------------------------------------------------------------
__global__ __launch_bounds__(256)
void gemm64_gelu(const unsigned short* __restrict__ A,
                 const unsigned short* __restrict__ Wt,
                 const float* __restrict__ bias,
                 unsigned short* __restrict__ out,
                 int M, int N, int K)
{
    __shared__ unsigned short As[64 * 32];
    __shared__ unsigned short Bs[64 * 32];

    const int tid = threadIdx.x;
    const int w = tid >> 6, l = tid & 63;
    const int lr = l & 15, lg = l >> 4;
    const int wr = w >> 1, wc = w & 1;
    const int m0 = blockIdx.x * 64, n0 = blockIdx.y * 64;

    f32x4 acc[2][2] = {};

    for (int k0 = 0; k0 < K; k0 += 32) {
        const int row = tid >> 2, ch = tid & 3;
        __syncthreads();
        GLD_LDS16(A  + (size_t)(m0 + row) * K + k0 + ch * 8, As + (w * 64) * 8);
        GLD_LDS16(Wt + (size_t)(n0 + row) * K + k0 + ch * 8, Bs + (w * 64) * 8);
        __syncthreads();

        short8 af[2], bfr[2];
        #pragma unroll
        for (int i = 0; i < 2; ++i)
            af[i] = *(const short8*)(As + ((wr * 32 + i * 16 + lr) * 32 + lg * 8));
        #pragma unroll
        for (int jj = 0; jj < 2; ++jj)
            bfr[jj] = *(const short8*)(Bs + ((wc * 32 + jj * 16 + lr) * 32 + lg * 8));
        #pragma unroll
        for (int i = 0; i < 2; ++i)
            #pragma unroll
            for (int jj = 0; jj < 2; ++jj)
                acc[i][jj] = MFMA16(af[i], bfr[jj], acc[i][jj]);
    }

    #pragma unroll
    for (int i = 0; i < 2; ++i)
        #pragma unroll
        for (int jj = 0; jj < 2; ++jj)
            #pragma unroll
            for (int r = 0; r < 4; ++r) {
                const int row = m0 + wr * 32 + i * 16 + lg * 4 + r;
                const int col = n0 + wc * 32 + jj * 16 + lr;
                const float c = acc[i][jj][r] + bias[col];
                const float g = 0.5f * c * (1.0f + erff(c * 0.70710678118654752f));
                out[(size_t)row * N + col] = f2bf(g);
            }
}

// ---------------------------------------------------------------------------
// Flash attention, swapped-operand MFMA, defer-max softmax (round-9 verified).
// THIS ROUND: 64 q-rows per block (was 128) -> grid 1024 = 4 blocks/CU
// (grid was the occupancy cap at 512 = 2/CU). LDS 40KB (4x40=160 fits).
// Per-wave softmax chain halves; 4 waves/SIMD interleave the serial
// fmax/shfl/exp chains. s_setprio(1) around MFMA clusters (T5, attn-proven).
// ---------------------------------------------------------------------------
__global__ __launch_bounds__(256)
void attn_mfma(const unsigned short* __restrict__ Qh,
               const unsigned short* __restrict__ Kh,
               const unsigned short* __restrict__ Vt,
               unsigned short* __restrict__ ctx)
{
    __shared__ unsigned short Ks[2][64 * 64];   // [row(seq)][d] swizzled (16KB)
    __shared__ unsigned short Vs[2][64 * 64];   // [row(d)][k]  swizzled (16KB)
    __shared__ unsigned short Ps[4][16 * 64];   // per-wave P[q][k] swizzled (8KB)

    const int tid = threadIdx.x;
    const int w = tid >> 6, l = tid & 63;
    const int lr = l & 15, lg = l >> 4;

    // XCD-chunked bijective swizzle (1024 blocks, 8 XCDs -> 128-block chunks)
    const int p = blockIdx.x + blockIdx.y * 32;
    const int id = (p & 7) * 128 + (p >> 3);
    const int q0 = (id & 31) << 6;         // 32 q-blocks of 64 rows per bh
    const int bh = id >> 5;

    const unsigned short* Qb = Qh + (size_t)bh * 131072;
    const char* Kb = (const char*)(Kh + (size_t)bh * 131072);
    const char* Vb = (const char*)(Vt + (size_t)bh * 131072);

    // stationary Q fragments: wave w owns q rows [q0+w*16, q0+w*16+16)
    short8 qf[2];
    #pragma unroll
    for (int c = 0; c < 2; ++c)
        qf[c] = *(const short8*)(Qb + (size_t)(q0 + w * 16 + lr) * 64 + c * 32 + lg * 8);

    float mrow = -1e30f;
    float lrow = 0.f;
    f32x4 accO[4] = {};   // [n(d)] : q=lg*4+r, d=n*16+lr

    auto STAGE = [&](int bf, int kt) {
        #pragma unroll
        for (int c = 0; c < 2; ++c) {
            const int cid = c * 256 + tid;
            const int row = cid >> 3, u = cid & 7;
            const int su = u ^ (row & 7);
            GLD_LDS16(Kb + (size_t)(kt + row) * 128 + su * 16,
                      (char*)&Ks[bf][0] + (c * 256 + w * 64) * 16);
            GLD_LDS16(Vb + (size_t)row * 4096 + (size_t)kt * 2 + su * 16,
                      (char*)&Vs[bf][0] + (c * 256 + w * 64) * 16);
        }
    };

    STAGE(0, 0);
    __syncthreads();

    int cur = 0;
    for (int t = 0; t < 32; ++t) {
        if (t < 31) STAGE(cur ^ 1, (t + 1) * 64);

        const char* Kbuf = (const char*)&Ks[cur][0];
        const char* Vbuf = (const char*)&Vs[cur][0];

        // --- QK^T (swapped): sf[n] = S^T tile, k=n*16+lg*4+r, q=lr
        f32x4 sf[4] = {};
        __builtin_amdgcn_s_setprio(1);
        #pragma unroll
        for (int n = 0; n < 4; ++n) {
            const int krow = n * 16 + lr;
            const short8 kf0 = *(const short8*)(Kbuf + krow * 128 + ((0 * 4 + lg) ^ (lr & 7)) * 16);
            const short8 kf1 = *(const short8*)(Kbuf + krow * 128 + ((1 * 4 + lg) ^ (lr & 7)) * 16);
            sf[n] = MFMA16(kf0, qf[0], sf[n]);
            sf[n] = MFMA16(kf1, qf[1], sf[n]);
        }
        __builtin_amdgcn_s_setprio(0);

        // --- V fragments: issue now so LDS latency hides under softmax work
        short8 vf[4][2];
        #pragma unroll
        for (int n = 0; n < 4; ++n) {
            const int drow = n * 16 + lr;
            vf[n][0] = *(const short8*)(Vbuf + drow * 128 + ((0 * 4 + lg) ^ (lr & 7)) * 16);
            vf[n][1] = *(const short8*)(Vbuf + drow * 128 + ((1 * 4 + lg) ^ (lr & 7)) * 16);
        }

        // --- softmax (exp2 domain), defer-max — round-9 verified logic
        float a = fmaxf(fmaxf(fmaxf(sf[0][0], sf[0][1]), fmaxf(sf[0][2], sf[0][3])),
                        fmaxf(fmaxf(sf[1][0], sf[1][1]), fmaxf(sf[1][2], sf[1][3])));
        float b2 = fmaxf(fmaxf(fmaxf(sf[2][0], sf[2][1]), fmaxf(sf[2][2], sf[2][3])),
                         fmaxf(fmaxf(sf[3][0], sf[3][1]), fmaxf(sf[3][2], sf[3][3])));
        float r2 = fmaxf(a, b2);
        r2 = fmaxf(r2, __shfl_xor(r2, 16));
        r2 = fmaxf(r2, __shfl_xor(r2, 32));
        const bool need = (r2 > mrow + DEFER_THR);
        if (__any(need)) {
            const float mnew = fmaxf(mrow, r2);
            const float rsc = ex2(mrow - mnew);
            lrow *= rsc;
            mrow = mnew;
            #pragma unroll
            for (int r = 0; r < 4; ++r) {
                const float rr = __shfl(rsc, (l & 48) | (lg * 4 + r));
                #pragma unroll
                for (int n = 0; n < 4; ++n) accO[n][r] *= rr;
            }
        }
        {
            const float m = mrow;
            float ls = lrow;
            char* pbase = (char*)&Ps[w][0] + lr * 128;
            #pragma unroll
            for (int n = 0; n < 4; ++n) {
                const float p0 = ex2(sf[n][0] - m);
                const float p1 = ex2(sf[n][1] - m);
                const float p2 = ex2(sf[n][2] - m);
                const float p3 = ex2(sf[n][3] - m);
                ls += (p0 + p1) + (p2 + p3);
                uint2 pk;
                pk.x = pk_bf16(p0, p1);
                pk.y = pk_bf16(p2, p3);
                *(uint2*)(pbase + (((n * 2 + (lg >> 1)) ^ (lr & 7)) * 16) + (lg & 1) * 8) = pk;
            }
            lrow = ls;
        }

        // scheduling fence between P stores and P loads
        asm volatile("" ::: "memory");

        // --- P read back as A-frag, same access type (uint2) as the stores
        short8 pf[2];
        {
            const char* pb = (const char*)&Ps[w][0] + lr * 128;
            #pragma unroll
            for (int c = 0; c < 2; ++c) {
                union { uint2 q2[2]; short8 s8; } cvt;
                const char* base = pb + (((c * 4 + lg) ^ (lr & 7)) * 16);
                cvt.q2[0] = *(const uint2*)(base);
                cvt.q2[1] = *(const uint2*)(base + 8);
                pf[c] = cvt.s8;
            }
        }

        // --- PV
        __builtin_amdgcn_s_setprio(1);
        #pragma unroll
        for (int n = 0; n < 4; ++n) {
            accO[n] = MFMA16(pf[0], vf[n][0], accO[n]);
            accO[n] = MFMA16(pf[1], vf[n][1], accO[n]);
        }
        __builtin_amdgcn_s_setprio(0);

        __syncthreads();      // next-tile stage complete + this tile's reads done
        cur ^= 1;
    }

    // epilogue: reduce l across lane groups, normalize, write ctx [B,S,D]
    const int b = bh >> 4, h = bh & 15;
    {
        float ls = lrow;
        ls += __shfl_xor(ls, 16);
        ls += __shfl_xor(ls, 32);
        const float inv = 1.0f / ls;
        #pragma unroll
        for (int r = 0; r < 4; ++r) {
            const float vr = __shfl(inv, (l & 48) | (lg * 4 + r));
            const int srow = q0 + w * 16 + lg * 4 + r;
            const size_t base = ((size_t)b * 2048 + srow) * 1024 + h * 64;
            #pragma unroll
            for (int n = 0; n < 4; ++n)
                ctx[base + n * 16 + lr] = f2bf(accO[n][r] * vr);
        }
    }
}

// ---------------------------------------------------------------------------
extern "C" void kernel_launch(void* const* d_in, const int* in_sizes, int n_in,
                              void* d_out, int out_size, void* d_ws, size_t ws_size,
                              hipStream_t stream) {
    const float* q   = (const float*)d_in[0];
    const float* k   = (const float*)d_in[1];
    const float* v   = (const float*)d_in[2];
    const float* Wq  = (const float*)d_in[3];
    const float* bq  = (const float*)d_in[4];
    const float* Wk  = (const float*)d_in[5];
    const float* bk  = (const float*)d_in[6];
    const float* Wv  = (const float*)d_in[7];
    const float* bv  = (const float*)d_in[8];
    const float* Wo  = (const float*)d_in[9];
    const float* bo  = (const float*)d_in[10];
    const float* Wad = (const float*)d_in[11];
    const float* bad = (const float*)d_in[12];
    const float* Wau = (const float*)d_in[13];
    const float* bau = (const float*)d_in[14];

    const int M = 4096, D = 1024, AD = 128;
    const size_t SZ = (size_t)M * D;

    char* p = (char*)d_ws;
    size_t off = 0;
    auto alloc = [&](size_t bytes) { void* r = p + off; off = (off + bytes + 255) & ~(size_t)255; return r; };
    unsigned short* xq   = (unsigned short*)alloc(SZ * 2);
    unsigned short* xk   = (unsigned short*)alloc(SZ * 2);
    unsigned short* xv   = (unsigned short*)alloc(SZ * 2);
    unsigned short* Wqb  = (unsigned short*)alloc((size_t)D * D * 2);
    unsigned short* Wkb  = (unsigned short*)alloc((size_t)D * D * 2);
    unsigned short* Wvb  = (unsigned short*)alloc((size_t)D * D * 2);
    unsigned short* Wob  = (unsigned short*)alloc((size_t)D * D * 2);
    unsigned short* Wadb = (unsigned short*)alloc((size_t)AD * D * 2);
    unsigned short* Waub = (unsigned short*)alloc((size_t)D * AD * 2);
    unsigned short* Qh   = (unsigned short*)alloc(SZ * 2);   // [B,H,S,64]
    unsigned short* Kh   = (unsigned short*)alloc(SZ * 2);   // [B,H,S,64]
    unsigned short* Vt   = (unsigned short*)alloc(SZ * 2);   // [B,H,64,S]
    unsigned short* ctx  = (unsigned short*)alloc(SZ * 2);   // [M,D]
    float*          outp = (float*)alloc(SZ * 4);            // O-proj fp32
    unsigned short* outb = (unsigned short*)alloc(SZ * 2);   // O-proj bf16
    unsigned short* a1   = (unsigned short*)alloc((size_t)M * AD * 2);

    CvtJobs j;
    j.src[0] = q;   j.dst[0] = xq;   j.n[0] = (int)SZ;   j.scale[0] = 1.f;
    j.src[1] = k;   j.dst[1] = xk;   j.n[1] = (int)SZ;   j.scale[1] = 1.f;
    j.src[2] = v;   j.dst[2] = xv;   j.n[2] = (int)SZ;   j.scale[2] = 1.f;
    j.src[3] = Wq;  j.dst[3] = Wqb;  j.n[3] = D * D;     j.scale[3] = QSCALE;
    j.src[4] = Wk;  j.dst[4] = Wkb;  j.n[4] = D * D;     j.scale[4] = 1.f;
    j.src[5] = Wv;  j.dst[5] = Wvb;  j.n[5] = D * D;     j.scale[5] = 1.f;
    j.src[6] = Wo;  j.dst[6] = Wob;  j.n[6] = D * D;     j.scale[6] = 1.f;
    j.src[7] = Wad; j.dst[7] = Wadb; j.n[7] = AD * D;    j.scale[7] = 1.f;
    j.src[8] = Wau; j.dst[8] = Waub; j.n[8] = D * AD;    j.scale[8] = 1.f;
    long long total = 3LL * SZ + 4LL * D * D + 2LL * AD * D;
    long long total4 = total / 4;
    convert_kernel<<<dim3((unsigned)((total4 + 255) / 256)), dim3(256), 0, stream>>>(j, total4);

    const dim3 blk(256);

    QKVArgs qa;
    qa.A[0] = xq;  qa.A[1] = xk;  qa.A[2] = xv;
    qa.W[0] = Wqb; qa.W[1] = Wkb; qa.W[2] = Wvb;
    qa.bias[0] = bq; qa.bias[1] = bk; qa.bias[2] = bv;
    qa.bscale[0] = QSCALE; qa.bscale[1] = 1.f; qa.bscale[2] = 1.f;
    qa.out[0] = Qh; qa.out[1] = Kh; qa.out[2] = Vt;
    gemm_qkv<<<dim3(M / 128, D / 128, 3), blk, 0, stream>>>(qa, M, D, D);

    // 1024 blocks (32 bh x 32 q-blocks of 64 rows) = 4 blocks/CU
    attn_mfma<<<dim3(32, 32), blk, 0, stream>>>(Qh, Kh, Vt, ctx);

    gemm_bf16<2><<<dim3(M / 128, D / 128), blk, 0, stream>>>(ctx, Wob, bo, outp, outb, M, D, D);
    gemm64_gelu<<<dim3(M / 64, AD / 64), blk, 0, stream>>>(outb, Wadb, bad, a1, M, AD, D);
    gemm_bf16<4><<<dim3(M / 128, D / 128), blk, 0, stream>>>(a1, Waub, bau, d_out, outp, M, D, AD);
}

// Round 11
// 164.029 us; speedup vs baseline: 1.1644x; 1.1644x over previous
//
#include <hip/hip_runtime.h>
#include <hip/hip_bf16.h>
#include <math.h>

// B=2, S=2048, D=1024, H=16, HD=64, AD=128, M=B*S=4096
typedef __attribute__((ext_vector_type(8))) short short8;
typedef __attribute__((ext_vector_type(4))) float f32x4;

#define MFMA16(a,b,c) __builtin_amdgcn_mfma_f32_16x16x32_bf16((a),(b),(c),0,0,0)

__device__ __forceinline__ unsigned short f2bf(float f){
    union { __hip_bfloat16 b; unsigned short u; } cv;
    cv.b = __float2bfloat16(f);
    return cv.u;
}
__device__ __forceinline__ unsigned pk_bf16(float a, float b){
    unsigned r;
    asm("v_cvt_pk_bf16_f32 %0, %1, %2" : "=v"(r) : "v"(a), "v"(b));
    return r;
}
// 2^x via v_exp_f32 (gfx950 hardware exp2)
__device__ __forceinline__ float ex2(float x){
    return __builtin_amdgcn_exp2f(x);
}

#define GLD_LDS16(g, s) \
    __builtin_amdgcn_global_load_lds((const __attribute__((address_space(1))) void*)(g), \
                                     (__attribute__((address_space(3))) void*)(s), 16, 0, 0)

// 0.125 (1/sqrt(HD)) * log2(e) folded into Wq/bq -> softmax uses exp2
#define QSCALE 0.18033688011112042f
#define DEFER_THR 11.0f

// ---------------------------------------------------------------------------
// fp32 -> bf16 batched conversion (9 tensors) with per-job scale
// ---------------------------------------------------------------------------
struct CvtJobs {
    const float* src[9];
    unsigned short* dst[9];
    float scale[9];
    int n[9];
};

__global__ __launch_bounds__(256)
void convert_kernel(CvtJobs j, long long total4) {
    long long i4 = (long long)blockIdx.x * blockDim.x + threadIdx.x;
    if (i4 >= total4) return;
    long long rem = i4 * 4;
    int job = 0;
    while (job < 9 && rem >= j.n[job]) { rem -= j.n[job]; ++job; }
    if (job >= 9) return;
    const float sc = j.scale[job];
    const float4 v = *(const float4*)(j.src[job] + rem);
    ushort4 o;
    o.x = f2bf(v.x * sc); o.y = f2bf(v.y * sc);
    o.z = f2bf(v.z * sc); o.w = f2bf(v.w * sc);
    *(ushort4*)(j.dst[job] + rem) = o;
}

// ---------------------------------------------------------------------------
// Shared 128x128 GEMM main loop (m97 structure + conflict-free XOR swizzle).
// ---------------------------------------------------------------------------
#define GEMM128_LOOP(Aptr, Bptr)                                                     \
    f32x4 acc[4][4] = {};                                                            \
    for (int k0 = 0; k0 < K; k0 += 32) {                                             \
        __syncthreads();                                                             \
        _Pragma("unroll")                                                            \
        for (int c = 0; c < 2; ++c) {                                                \
            const int id = c * 256 + tid;                                            \
            const int row = id >> 2, u = id & 3;                                     \
            const int su = u ^ ((row >> 1) & 3);                                     \
            GLD_LDS16((const char*)(Aptr) + ((size_t)(m0 + row) * K + k0) * 2 + su * 16, \
                      (char*)As + (c * 256 + w * 64) * 16);                          \
            GLD_LDS16((const char*)(Bptr) + ((size_t)(n0 + row) * K + k0) * 2 + su * 16, \
                      (char*)Bs + (c * 256 + w * 64) * 16);                          \
        }                                                                            \
        __syncthreads();                                                             \
        short8 af[4], bfr[4];                                                        \
        _Pragma("unroll")                                                            \
        for (int i = 0; i < 4; ++i)                                                  \
            af[i] = *(const short8*)((const char*)As + (wr * 64 + i * 16 + lr) * 64 + ru * 16); \
        _Pragma("unroll")                                                            \
        for (int jj = 0; jj < 4; ++jj)                                               \
            bfr[jj] = *(const short8*)((const char*)Bs + (wc * 64 + jj * 16 + lr) * 64 + ru * 16); \
        _Pragma("unroll")                                                            \
        for (int i = 0; i < 4; ++i)                                                  \
            _Pragma("unroll")                                                        \
            for (int jj = 0; jj < 4; ++jj)                                           \
                acc[i][jj] = MFMA16(af[i], bfr[jj], acc[i][jj]);                     \
    }

// ---------------------------------------------------------------------------
// Fused QKV projection. grid (M/128, D/128, 3).
// ---------------------------------------------------------------------------
struct QKVArgs {
    const unsigned short* A[3];
    const unsigned short* W[3];
    const float* bias[3];
    float bscale[3];
    unsigned short* out[3];
};

__global__ __launch_bounds__(256)
void gemm_qkv(QKVArgs ar, int M, int N, int K)
{
    __shared__ unsigned short As[128 * 32];
    __shared__ unsigned short Bs[128 * 32];

    const int z = blockIdx.z;
    const unsigned short* A = ar.A[z];
    const unsigned short* W = ar.W[z];
    const int tid = threadIdx.x;
    const int w = tid >> 6, l = tid & 63;
    const int lr = l & 15, lg = l >> 4;
    const int wr = w >> 1, wc = w & 1;
    const int m0 = blockIdx.x * 128, n0 = blockIdx.y * 128;
    const int ru = lg ^ ((lr >> 1) & 3);

    GEMM128_LOOP(A, W)

    const float* bias = ar.bias[z];
    const float bsc = ar.bscale[z];
    unsigned short* out = ar.out[z];
    #pragma unroll
    for (int i = 0; i < 4; ++i)
        #pragma unroll
        for (int jj = 0; jj < 4; ++jj)
            #pragma unroll
            for (int r = 0; r < 4; ++r) {
                const int row = m0 + wr * 64 + i * 16 + lg * 4 + r;
                const int col = n0 + wc * 64 + jj * 16 + lr;
                const float c = acc[i][jj][r] + bias[col] * bsc;
                const int b = row >> 11, s = row & 2047, h = col >> 6, hd = col & 63;
                if (z < 2)
                    out[((((size_t)(b * 16 + h)) * 2048 + s) << 6) + hd] = f2bf(c);
                else
                    out[((((size_t)(b * 16 + h)) * 64 + hd) << 11) + s] = f2bf(c);
            }
}

// ---------------------------------------------------------------------------
// Generic 128x128 GEMM. MODE 2: fp32 out0 + bf16 out1 (O-proj).
// MODE 4: + fp32 residual(out1) -> fp32 out0 (adapter up).
// ---------------------------------------------------------------------------
template<int MODE>
__global__ __launch_bounds__(256)
void gemm_bf16(const unsigned short* __restrict__ A,
               const unsigned short* __restrict__ Wt,
               const float* __restrict__ bias,
               void* __restrict__ out0,
               void* __restrict__ out1,
               int M, int N, int K)
{
    __shared__ unsigned short As[128 * 32];
    __shared__ unsigned short Bs[128 * 32];

    const int tid = threadIdx.x;
    const int w = tid >> 6, l = tid & 63;
    const int lr = l & 15, lg = l >> 4;
    const int wr = w >> 1, wc = w & 1;
    const int m0 = blockIdx.x * 128, n0 = blockIdx.y * 128;
    const int ru = lg ^ ((lr >> 1) & 3);

    GEMM128_LOOP(A, Wt)

    #pragma unroll
    for (int i = 0; i < 4; ++i)
        #pragma unroll
        for (int jj = 0; jj < 4; ++jj)
            #pragma unroll
            for (int r = 0; r < 4; ++r) {
                const int row = m0 + wr * 64 + i * 16 + lg * 4 + r;
                const int col = n0 + wc * 64 + jj * 16 + lr;
                const float c = acc[i][jj][r] + bias[col];
                if (MODE == 2) {
                    ((float*)out0)[(size_t)row * N + col] = c;
                    ((unsigned short*)out1)[(size_t)row * N + col] = f2bf(c);
                } else {
                    ((float*)out0)[(size_t)row * N + col] =
                        c + ((const float*)out1)[(size_t)row * N + col];
                }
            }
}

// ---------------------------------------------------------------------------
// 64x64-tile GEMM + exact GELU (adapter down, N=128)
// ---------------------------------------------------------------------------
__global__ __launch_bounds__(256)
void gemm64_gelu(const unsigned short* __restrict__ A,
                 const unsigned short* __restrict__ Wt,
                 const float* __restrict__ bias,
                 unsigned short* __restrict__ out,
                 int M, int N, int K)
{
    __shared__ unsigned short As[64 * 32];
    __shared__ unsigned short Bs[64 * 32];

    const int tid = threadIdx.x;
    const int w = tid >> 6, l = tid & 63;
    const int lr = l & 15, lg = l >> 4;
    const int wr = w >> 1, wc = w & 1;
    const int m0 = blockIdx.x * 64, n0 = blockIdx.y * 64;

    f32x4 acc[2][2] = {};

    for (int k0 = 0; k0 < K; k0 += 32) {
        const int row = tid >> 2, ch = tid & 3;
        __syncthreads();
        GLD_LDS16(A  + (size_t)(m0 + row) * K + k0 + ch * 8, As + (w * 64) * 8);
        GLD_LDS16(Wt + (size_t)(n0 + row) * K + k0 + ch * 8, Bs + (w * 64) * 8);
        __syncthreads();

        short8 af[2], bfr[2];
        #pragma unroll
        for (int i = 0; i < 2; ++i)
            af[i] = *(const short8*)(As + ((wr * 32 + i * 16 + lr) * 32 + lg * 8));
        #pragma unroll
        for (int jj = 0; jj < 2; ++jj)
            bfr[jj] = *(const short8*)(Bs + ((wc * 32 + jj * 16 + lr) * 32 + lg * 8));
        #pragma unroll
        for (int i = 0; i < 2; ++i)
            #pragma unroll
            for (int jj = 0; jj < 2; ++jj)
                acc[i][jj] = MFMA16(af[i], bfr[jj], acc[i][jj]);
    }

    #pragma unroll
    for (int i = 0; i < 2; ++i)
        #pragma unroll
        for (int jj = 0; jj < 2; ++jj)
            #pragma unroll
            for (int r = 0; r < 4; ++r) {
                const int row = m0 + wr * 32 + i * 16 + lg * 4 + r;
                const int col = n0 + wc * 32 + jj * 16 + lr;
                const float c = acc[i][jj][r] + bias[col];
                const float g = 0.5f * c * (1.0f + erff(c * 0.70710678118654752f));
                out[(size_t)row * N + col] = f2bf(g);
            }
}

// ---------------------------------------------------------------------------
// Flash attention, swapped-operand MFMA, defer-max softmax (round-9 verified).
// THIS ROUND: 512 threads / 8 waves per 128-q-row block (round-9 geometry,
// round-10 per-wave path). Grid stays 512 (2 blocks/CU) but waves/CU = 16
// (4/SIMD) — TLP to interleave the serial softmax chains WITHOUT doubling
// staging or barrier cost per q-row (round-10's mistake). LDS 48KB.
// ---------------------------------------------------------------------------
__global__ __launch_bounds__(512)
void attn_mfma(const unsigned short* __restrict__ Qh,
               const unsigned short* __restrict__ Kh,
               const unsigned short* __restrict__ Vt,
               unsigned short* __restrict__ ctx)
{
    __shared__ unsigned short Ks[2][64 * 64];   // [row(seq)][d] swizzled (16KB)
    __shared__ unsigned short Vs[2][64 * 64];   // [row(d)][k]  swizzled (16KB)
    __shared__ unsigned short Ps[8][16 * 64];   // per-wave P[q][k] swizzled (16KB)

    const int tid = threadIdx.x;
    const int w = tid >> 6, l = tid & 63;
    const int lr = l & 15, lg = l >> 4;

    // XCD-chunked bijective swizzle (512 blocks, 8 XCDs -> 64-block chunks)
    const int p = blockIdx.x + blockIdx.y * 16;
    const int id = (p & 7) * 64 + (p >> 3);
    const int q0 = (id & 15) << 7;         // 16 q-blocks of 128 rows per bh
    const int bh = id >> 4;

    const unsigned short* Qb = Qh + (size_t)bh * 131072;
    const char* Kb = (const char*)(Kh + (size_t)bh * 131072);
    const char* Vb = (const char*)(Vt + (size_t)bh * 131072);

    // stationary Q fragments: wave w owns q rows [q0+w*16, q0+w*16+16)
    short8 qf[2];
    #pragma unroll
    for (int c = 0; c < 2; ++c)
        qf[c] = *(const short8*)(Qb + (size_t)(q0 + w * 16 + lr) * 64 + c * 32 + lg * 8);

    float mrow = -1e30f;
    float lrow = 0.f;
    f32x4 accO[4] = {};   // [n(d)] : q=lg*4+r, d=n*16+lr

    // 512 threads: each issues exactly 1 K-chunk + 1 V-chunk (512 x 16B each)
    auto STAGE = [&](int bf, int kt) {
        const int row = tid >> 3, u = tid & 7;
        const int su = u ^ (row & 7);
        GLD_LDS16(Kb + (size_t)(kt + row) * 128 + su * 16,
                  (char*)&Ks[bf][0] + (w * 64) * 16);
        GLD_LDS16(Vb + (size_t)row * 4096 + (size_t)kt * 2 + su * 16,
                  (char*)&Vs[bf][0] + (w * 64) * 16);
    };

    STAGE(0, 0);
    __syncthreads();

    int cur = 0;
    for (int t = 0; t < 32; ++t) {
        if (t < 31) STAGE(cur ^ 1, (t + 1) * 64);

        const char* Kbuf = (const char*)&Ks[cur][0];
        const char* Vbuf = (const char*)&Vs[cur][0];

        // --- QK^T (swapped): sf[n] = S^T tile, k=n*16+lg*4+r, q=lr
        f32x4 sf[4] = {};
        __builtin_amdgcn_s_setprio(1);
        #pragma unroll
        for (int n = 0; n < 4; ++n) {
            const int krow = n * 16 + lr;
            const short8 kf0 = *(const short8*)(Kbuf + krow * 128 + ((0 * 4 + lg) ^ (lr & 7)) * 16);
            const short8 kf1 = *(const short8*)(Kbuf + krow * 128 + ((1 * 4 + lg) ^ (lr & 7)) * 16);
            sf[n] = MFMA16(kf0, qf[0], sf[n]);
            sf[n] = MFMA16(kf1, qf[1], sf[n]);
        }
        __builtin_amdgcn_s_setprio(0);

        // --- V fragments: issue now so LDS latency hides under softmax work
        short8 vf[4][2];
        #pragma unroll
        for (int n = 0; n < 4; ++n) {
            const int drow = n * 16 + lr;
            vf[n][0] = *(const short8*)(Vbuf + drow * 128 + ((0 * 4 + lg) ^ (lr & 7)) * 16);
            vf[n][1] = *(const short8*)(Vbuf + drow * 128 + ((1 * 4 + lg) ^ (lr & 7)) * 16);
        }

        // --- softmax (exp2 domain), defer-max — verified logic
        float a = fmaxf(fmaxf(fmaxf(sf[0][0], sf[0][1]), fmaxf(sf[0][2], sf[0][3])),
                        fmaxf(fmaxf(sf[1][0], sf[1][1]), fmaxf(sf[1][2], sf[1][3])));
        float b2 = fmaxf(fmaxf(fmaxf(sf[2][0], sf[2][1]), fmaxf(sf[2][2], sf[2][3])),
                         fmaxf(fmaxf(sf[3][0], sf[3][1]), fmaxf(sf[3][2], sf[3][3])));
        float r2 = fmaxf(a, b2);
        r2 = fmaxf(r2, __shfl_xor(r2, 16));
        r2 = fmaxf(r2, __shfl_xor(r2, 32));
        const bool need = (r2 > mrow + DEFER_THR);
        if (__any(need)) {
            const float mnew = fmaxf(mrow, r2);
            const float rsc = ex2(mrow - mnew);
            lrow *= rsc;
            mrow = mnew;
            #pragma unroll
            for (int r = 0; r < 4; ++r) {
                const float rr = __shfl(rsc, (l & 48) | (lg * 4 + r));
                #pragma unroll
                for (int n = 0; n < 4; ++n) accO[n][r] *= rr;
            }
        }
        {
            const float m = mrow;
            float ls = lrow;
            char* pbase = (char*)&Ps[w][0] + lr * 128;
            #pragma unroll
            for (int n = 0; n < 4; ++n) {
                const float p0 = ex2(sf[n][0] - m);
                const float p1 = ex2(sf[n][1] - m);
                const float p2 = ex2(sf[n][2] - m);
                const float p3 = ex2(sf[n][3] - m);
                ls += (p0 + p1) + (p2 + p3);
                uint2 pk;
                pk.x = pk_bf16(p0, p1);
                pk.y = pk_bf16(p2, p3);
                *(uint2*)(pbase + (((n * 2 + (lg >> 1)) ^ (lr & 7)) * 16) + (lg & 1) * 8) = pk;
            }
            lrow = ls;
        }

        // scheduling fence between P stores and P loads
        asm volatile("" ::: "memory");

        // --- P read back as A-frag, same access type (uint2) as the stores
        short8 pf[2];
        {
            const char* pb = (const char*)&Ps[w][0] + lr * 128;
            #pragma unroll
            for (int c = 0; c < 2; ++c) {
                union { uint2 q2[2]; short8 s8; } cvt;
                const char* base = pb + (((c * 4 + lg) ^ (lr & 7)) * 16);
                cvt.q2[0] = *(const uint2*)(base);
                cvt.q2[1] = *(const uint2*)(base + 8);
                pf[c] = cvt.s8;
            }
        }

        // --- PV
        __builtin_amdgcn_s_setprio(1);
        #pragma unroll
        for (int n = 0; n < 4; ++n) {
            accO[n] = MFMA16(pf[0], vf[n][0], accO[n]);
            accO[n] = MFMA16(pf[1], vf[n][1], accO[n]);
        }
        __builtin_amdgcn_s_setprio(0);

        __syncthreads();      // next-tile stage complete + this tile's reads done
        cur ^= 1;
    }

    // epilogue: reduce l across lane groups, normalize, write ctx [B,S,D]
    const int b = bh >> 4, h = bh & 15;
    {
        float ls = lrow;
        ls += __shfl_xor(ls, 16);
        ls += __shfl_xor(ls, 32);
        const float inv = 1.0f / ls;
        #pragma unroll
        for (int r = 0; r < 4; ++r) {
            const float vr = __shfl(inv, (l & 48) | (lg * 4 + r));
            const int srow = q0 + w * 16 + lg * 4 + r;
            const size_t base = ((size_t)b * 2048 + srow) * 1024 + h * 64;
            #pragma unroll
            for (int n = 0; n < 4; ++n)
                ctx[base + n * 16 + lr] = f2bf(accO[n][r] * vr);
        }
    }
}

// ---------------------------------------------------------------------------
extern "C" void kernel_launch(void* const* d_in, const int* in_sizes, int n_in,
                              void* d_out, int out_size, void* d_ws, size_t ws_size,
                              hipStream_t stream) {
    const float* q   = (const float*)d_in[0];
    const float* k   = (const float*)d_in[1];
    const float* v   = (const float*)d_in[2];
    const float* Wq  = (const float*)d_in[3];
    const float* bq  = (const float*)d_in[4];
    const float* Wk  = (const float*)d_in[5];
    const float* bk  = (const float*)d_in[6];
    const float* Wv  = (const float*)d_in[7];
    const float* bv  = (const float*)d_in[8];
    const float* Wo  = (const float*)d_in[9];
    const float* bo  = (const float*)d_in[10];
    const float* Wad = (const float*)d_in[11];
    const float* bad = (const float*)d_in[12];
    const float* Wau = (const float*)d_in[13];
    const float* bau = (const float*)d_in[14];

    const int M = 4096, D = 1024, AD = 128;
    const size_t SZ = (size_t)M * D;

    char* p = (char*)d_ws;
    size_t off = 0;
    auto alloc = [&](size_t bytes) { void* r = p + off; off = (off + bytes + 255) & ~(size_t)255; return r; };
    unsigned short* xq   = (unsigned short*)alloc(SZ * 2);
    unsigned short* xk   = (unsigned short*)alloc(SZ * 2);
    unsigned short* xv   = (unsigned short*)alloc(SZ * 2);
    unsigned short* Wqb  = (unsigned short*)alloc((size_t)D * D * 2);
    unsigned short* Wkb  = (unsigned short*)alloc((size_t)D * D * 2);
    unsigned short* Wvb  = (unsigned short*)alloc((size_t)D * D * 2);
    unsigned short* Wob  = (unsigned short*)alloc((size_t)D * D * 2);
    unsigned short* Wadb = (unsigned short*)alloc((size_t)AD * D * 2);
    unsigned short* Waub = (unsigned short*)alloc((size_t)D * AD * 2);
    unsigned short* Qh   = (unsigned short*)alloc(SZ * 2);   // [B,H,S,64]
    unsigned short* Kh   = (unsigned short*)alloc(SZ * 2);   // [B,H,S,64]
    unsigned short* Vt   = (unsigned short*)alloc(SZ * 2);   // [B,H,64,S]
    unsigned short* ctx  = (unsigned short*)alloc(SZ * 2);   // [M,D]
    float*          outp = (float*)alloc(SZ * 4);            // O-proj fp32
    unsigned short* outb = (unsigned short*)alloc(SZ * 2);   // O-proj bf16
    unsigned short* a1   = (unsigned short*)alloc((size_t)M * AD * 2);

    CvtJobs j;
    j.src[0] = q;   j.dst[0] = xq;   j.n[0] = (int)SZ;   j.scale[0] = 1.f;
    j.src[1] = k;   j.dst[1] = xk;   j.n[1] = (int)SZ;   j.scale[1] = 1.f;
    j.src[2] = v;   j.dst[2] = xv;   j.n[2] = (int)SZ;   j.scale[2] = 1.f;
    j.src[3] = Wq;  j.dst[3] = Wqb;  j.n[3] = D * D;     j.scale[3] = QSCALE;
    j.src[4] = Wk;  j.dst[4] = Wkb;  j.n[4] = D * D;     j.scale[4] = 1.f;
    j.src[5] = Wv;  j.dst[5] = Wvb;  j.n[5] = D * D;     j.scale[5] = 1.f;
    j.src[6] = Wo;  j.dst[6] = Wob;  j.n[6] = D * D;     j.scale[6] = 1.f;
    j.src[7] = Wad; j.dst[7] = Wadb; j.n[7] = AD * D;    j.scale[7] = 1.f;
    j.src[8] = Wau; j.dst[8] = Waub; j.n[8] = D * AD;    j.scale[8] = 1.f;
    long long total = 3LL * SZ + 4LL * D * D + 2LL * AD * D;
    long long total4 = total / 4;
    convert_kernel<<<dim3((unsigned)((total4 + 255) / 256)), dim3(256), 0, stream>>>(j, total4);

    const dim3 blk(256);

    QKVArgs qa;
    qa.A[0] = xq;  qa.A[1] = xk;  qa.A[2] = xv;
    qa.W[0] = Wqb; qa.W[1] = Wkb; qa.W[2] = Wvb;
    qa.bias[0] = bq; qa.bias[1] = bk; qa.bias[2] = bv;
    qa.bscale[0] = QSCALE; qa.bscale[1] = 1.f; qa.bscale[2] = 1.f;
    qa.out[0] = Qh; qa.out[1] = Kh; qa.out[2] = Vt;
    gemm_qkv<<<dim3(M / 128, D / 128, 3), blk, 0, stream>>>(qa, M, D, D);

    // 512 blocks (32 bh x 16 q-blocks of 128 rows), 512 threads / 8 waves each
    attn_mfma<<<dim3(16, 32), dim3(512), 0, stream>>>(Qh, Kh, Vt, ctx);

    gemm_bf16<2><<<dim3(M / 128, D / 128), blk, 0, stream>>>(ctx, Wob, bo, outp, outb, M, D, D);
    gemm64_gelu<<<dim3(M / 64, AD / 64), blk, 0, stream>>>(outb, Wadb, bad, a1, M, AD, D);
    gemm_bf16<4><<<dim3(M / 128, D / 128), blk, 0, stream>>>(a1, Waub, bau, d_out, outp, M, D, AD);
}

// Round 12
// 153.415 us; speedup vs baseline: 1.2450x; 1.0692x over previous
//
#include <hip/hip_runtime.h>
#include <hip/hip_bf16.h>
#include <math.h>

// B=2, S=2048, D=1024, H=16, HD=64, AD=128, M=B*S=4096
typedef __attribute__((ext_vector_type(8))) short short8;
typedef __attribute__((ext_vector_type(4))) float f32x4;

#define MFMA16(a,b,c) __builtin_amdgcn_mfma_f32_16x16x32_bf16((a),(b),(c),0,0,0)

__device__ __forceinline__ unsigned short f2bf(float f){
    union { __hip_bfloat16 b; unsigned short u; } cv;
    cv.b = __float2bfloat16(f);
    return cv.u;
}
__device__ __forceinline__ unsigned pk_bf16(float a, float b){
    unsigned r;
    asm("v_cvt_pk_bf16_f32 %0, %1, %2" : "=v"(r) : "v"(a), "v"(b));
    return r;
}
// 2^x via v_exp_f32 (gfx950 hardware exp2)
__device__ __forceinline__ float ex2(float x){
    return __builtin_amdgcn_exp2f(x);
}

#define GLD_LDS16(g, s) \
    __builtin_amdgcn_global_load_lds((const __attribute__((address_space(1))) void*)(g), \
                                     (__attribute__((address_space(3))) void*)(s), 16, 0, 0)

// 0.125 (1/sqrt(HD)) * log2(e) folded into Wq/bq -> softmax uses exp2
#define QSCALE 0.18033688011112042f
#define DEFER_THR 11.0f

// ---------------------------------------------------------------------------
// fp32 -> bf16 batched conversion (WEIGHTS ONLY now: 6 tensors)
// ---------------------------------------------------------------------------
struct CvtJobs {
    const float* src[6];
    unsigned short* dst[6];
    float scale[6];
    int n[6];
};

__global__ __launch_bounds__(256)
void convert_kernel(CvtJobs j, long long total4) {
    long long i4 = (long long)blockIdx.x * blockDim.x + threadIdx.x;
    if (i4 >= total4) return;
    long long rem = i4 * 4;
    int job = 0;
    while (job < 6 && rem >= j.n[job]) { rem -= j.n[job]; ++job; }
    if (job >= 6) return;
    const float sc = j.scale[job];
    const float4 v = *(const float4*)(j.src[job] + rem);
    ushort4 o;
    o.x = f2bf(v.x * sc); o.y = f2bf(v.y * sc);
    o.z = f2bf(v.z * sc); o.w = f2bf(v.w * sc);
    *(ushort4*)(j.dst[job] + rem) = o;
}

// ---------------------------------------------------------------------------
// Fused QKV projection, double-buffered, A read DIRECTLY as fp32 (staged to
// LDS via global_load_lds, converted to bf16 at frag-load with cvt_pk — same
// RNE as the old convert kernel, bit-identical numerics).
// BM=128, BN=128, BK=32; grid (M/128, D/128, 3). LDS 48KB.
// z=0,1 -> head layout [b,h,s,64]; z=2 -> transposed [b,h,hd,s] (V).
// ---------------------------------------------------------------------------
struct QKVArgs {
    const float* A[3];                 // fp32 activations (q,k,v)
    const unsigned short* W[3];        // bf16 weights
    const float* bias[3];
    float bscale[3];
    unsigned short* out[3];
};

__global__ __launch_bounds__(256)
void gemm_qkv(QKVArgs ar, int M, int N, int K)
{
    __shared__ float          Asf[2][128 * 32];    // fp32 A tiles (2 x 16KB)
    __shared__ unsigned short Bs[2][128 * 32];     // bf16 W tiles (2 x 8KB)

    const int z = blockIdx.z;
    const float* A = ar.A[z];
    const unsigned short* W = ar.W[z];
    const int tid = threadIdx.x;
    const int w = tid >> 6, l = tid & 63;
    const int lr = l & 15, lg = l >> 4;
    const int wr = w >> 1, wc = w & 1;
    const int m0 = blockIdx.x * 128, n0 = blockIdx.y * 128;
    const int ru = lg ^ ((lr >> 1) & 3);

    auto STAGE = [&](int bf, int k0) {
        // A tile: 128 rows x 32 k x 4B = 16KB = 1024 chunks, 4/thread
        #pragma unroll
        for (int c = 0; c < 4; ++c) {
            const int cid = c * 256 + tid;
            const int row = cid >> 3, u = cid & 7;       // 8 chunks per row
            const int su = u ^ (row & 7);
            GLD_LDS16((const char*)A + ((size_t)(m0 + row) * K + k0) * 4 + su * 16,
                      (char*)&Asf[bf][0] + (c * 256 + w * 64) * 16);
        }
        // B tile: 128 rows x 32 k x 2B = 8KB = 512 chunks, 2/thread
        #pragma unroll
        for (int c = 0; c < 2; ++c) {
            const int cid = c * 256 + tid;
            const int row = cid >> 2, u = cid & 3;       // 4 chunks per row
            const int su = u ^ ((row >> 1) & 3);
            GLD_LDS16((const char*)W + ((size_t)(n0 + row) * K + k0) * 2 + su * 16,
                      (char*)&Bs[bf][0] + (c * 256 + w * 64) * 16);
        }
    };

    f32x4 acc[4][4] = {};
    STAGE(0, 0);
    __syncthreads();
    int cur = 0;

    for (int k0 = 0; k0 < K; k0 += 32) {
        if (k0 + 32 < K) STAGE(cur ^ 1, k0 + 32);

        short8 af[4], bfr[4];
        #pragma unroll
        for (int i = 0; i < 4; ++i) {
            const int row = wr * 64 + i * 16 + lr;
            const char* rb = (const char*)&Asf[cur][0] + row * 128;
            const float4 f0 = *(const float4*)(rb + (((lg * 2 + 0) ^ (row & 7)) * 16));
            const float4 f1 = *(const float4*)(rb + (((lg * 2 + 1) ^ (row & 7)) * 16));
            union { unsigned u[4]; short8 s; } cv;
            cv.u[0] = pk_bf16(f0.x, f0.y);
            cv.u[1] = pk_bf16(f0.z, f0.w);
            cv.u[2] = pk_bf16(f1.x, f1.y);
            cv.u[3] = pk_bf16(f1.z, f1.w);
            af[i] = cv.s;
        }
        #pragma unroll
        for (int jj = 0; jj < 4; ++jj)
            bfr[jj] = *(const short8*)((const char*)&Bs[cur][0] + (wc * 64 + jj * 16 + lr) * 64 + ru * 16);
        #pragma unroll
        for (int i = 0; i < 4; ++i)
            #pragma unroll
            for (int jj = 0; jj < 4; ++jj)
                acc[i][jj] = MFMA16(af[i], bfr[jj], acc[i][jj]);

        __syncthreads();
        cur ^= 1;
    }

    const float* bias = ar.bias[z];
    const float bsc = ar.bscale[z];
    unsigned short* out = ar.out[z];
    #pragma unroll
    for (int i = 0; i < 4; ++i)
        #pragma unroll
        for (int jj = 0; jj < 4; ++jj)
            #pragma unroll
            for (int r = 0; r < 4; ++r) {
                const int row = m0 + wr * 64 + i * 16 + lg * 4 + r;
                const int col = n0 + wc * 64 + jj * 16 + lr;
                const float c = acc[i][jj][r] + bias[col] * bsc;
                const int b = row >> 11, s = row & 2047, h = col >> 6, hd = col & 63;
                if (z < 2)
                    out[((((size_t)(b * 16 + h)) * 2048 + s) << 6) + hd] = f2bf(c);
                else
                    out[((((size_t)(b * 16 + h)) * 64 + hd) << 11) + s] = f2bf(c);
            }
}

// ---------------------------------------------------------------------------
// Generic 128x128 GEMM (bf16 A), double-buffered. MODE 2: fp32 out0 + bf16
// out1 (O-proj). MODE 4: + fp32 residual(out1) -> fp32 out0 (adapter up).
// ---------------------------------------------------------------------------
template<int MODE>
__global__ __launch_bounds__(256)
void gemm_bf16(const unsigned short* __restrict__ A,
               const unsigned short* __restrict__ Wt,
               const float* __restrict__ bias,
               void* __restrict__ out0,
               void* __restrict__ out1,
               int M, int N, int K)
{
    __shared__ unsigned short As[2][128 * 32];
    __shared__ unsigned short Bs[2][128 * 32];

    const int tid = threadIdx.x;
    const int w = tid >> 6, l = tid & 63;
    const int lr = l & 15, lg = l >> 4;
    const int wr = w >> 1, wc = w & 1;
    const int m0 = blockIdx.x * 128, n0 = blockIdx.y * 128;
    const int ru = lg ^ ((lr >> 1) & 3);

    auto STAGE = [&](int bf, int k0) {
        #pragma unroll
        for (int c = 0; c < 2; ++c) {
            const int cid = c * 256 + tid;
            const int row = cid >> 2, u = cid & 3;
            const int su = u ^ ((row >> 1) & 3);
            GLD_LDS16((const char*)A  + ((size_t)(m0 + row) * K + k0) * 2 + su * 16,
                      (char*)&As[bf][0] + (c * 256 + w * 64) * 16);
            GLD_LDS16((const char*)Wt + ((size_t)(n0 + row) * K + k0) * 2 + su * 16,
                      (char*)&Bs[bf][0] + (c * 256 + w * 64) * 16);
        }
    };

    f32x4 acc[4][4] = {};
    STAGE(0, 0);
    __syncthreads();
    int cur = 0;

    for (int k0 = 0; k0 < K; k0 += 32) {
        if (k0 + 32 < K) STAGE(cur ^ 1, k0 + 32);

        short8 af[4], bfr[4];
        #pragma unroll
        for (int i = 0; i < 4; ++i)
            af[i] = *(const short8*)((const char*)&As[cur][0] + (wr * 64 + i * 16 + lr) * 64 + ru * 16);
        #pragma unroll
        for (int jj = 0; jj < 4; ++jj)
            bfr[jj] = *(const short8*)((const char*)&Bs[cur][0] + (wc * 64 + jj * 16 + lr) * 64 + ru * 16);
        #pragma unroll
        for (int i = 0; i < 4; ++i)
            #pragma unroll
            for (int jj = 0; jj < 4; ++jj)
                acc[i][jj] = MFMA16(af[i], bfr[jj], acc[i][jj]);

        __syncthreads();
        cur ^= 1;
    }

    #pragma unroll
    for (int i = 0; i < 4; ++i)
        #pragma unroll
        for (int jj = 0; jj < 4; ++jj)
            #pragma unroll
            for (int r = 0; r < 4; ++r) {
                const int row = m0 + wr * 64 + i * 16 + lg * 4 + r;
                const int col = n0 + wc * 64 + jj * 16 + lr;
                const float c = acc[i][jj][r] + bias[col];
                if (MODE == 2) {
                    ((float*)out0)[(size_t)row * N + col] = c;
                    ((unsigned short*)out1)[(size_t)row * N + col] = f2bf(c);
                } else {
                    ((float*)out0)[(size_t)row * N + col] =
                        c + ((const float*)out1)[(size_t)row * N + col];
                }
            }
}

// ---------------------------------------------------------------------------
// 64x64-tile GEMM + exact GELU (adapter down, N=128), double-buffered.
// ---------------------------------------------------------------------------
__global__ __launch_bounds__(256)
void gemm64_gelu(const unsigned short* __restrict__ A,
                 const unsigned short* __restrict__ Wt,
                 const float* __restrict__ bias,
                 unsigned short* __restrict__ out,
                 int M, int N, int K)
{
    __shared__ unsigned short As[2][64 * 32];
    __shared__ unsigned short Bs[2][64 * 32];

    const int tid = threadIdx.x;
    const int w = tid >> 6, l = tid & 63;
    const int lr = l & 15, lg = l >> 4;
    const int wr = w >> 1, wc = w & 1;
    const int m0 = blockIdx.x * 64, n0 = blockIdx.y * 64;

    auto STAGE = [&](int bf, int k0) {
        const int row = tid >> 2, ch = tid & 3;
        GLD_LDS16(A  + (size_t)(m0 + row) * K + k0 + ch * 8, &As[bf][0] + (w * 64) * 8);
        GLD_LDS16(Wt + (size_t)(n0 + row) * K + k0 + ch * 8, &Bs[bf][0] + (w * 64) * 8);
    };

    f32x4 acc[2][2] = {};
    STAGE(0, 0);
    __syncthreads();
    int cur = 0;

    for (int k0 = 0; k0 < K; k0 += 32) {
        if (k0 + 32 < K) STAGE(cur ^ 1, k0 + 32);

        short8 af[2], bfr[2];
        #pragma unroll
        for (int i = 0; i < 2; ++i)
            af[i] = *(const short8*)(&As[cur][0] + ((wr * 32 + i * 16 + lr) * 32 + lg * 8));
        #pragma unroll
        for (int jj = 0; jj < 2; ++jj)
            bfr[jj] = *(const short8*)(&Bs[cur][0] + ((wc * 32 + jj * 16 + lr) * 32 + lg * 8));
        #pragma unroll
        for (int i = 0; i < 2; ++i)
            #pragma unroll
            for (int jj = 0; jj < 2; ++jj)
                acc[i][jj] = MFMA16(af[i], bfr[jj], acc[i][jj]);

        __syncthreads();
        cur ^= 1;
    }

    #pragma unroll
    for (int i = 0; i < 2; ++i)
        #pragma unroll
        for (int jj = 0; jj < 2; ++jj)
            #pragma unroll
            for (int r = 0; r < 4; ++r) {
                const int row = m0 + wr * 32 + i * 16 + lg * 4 + r;
                const int col = n0 + wc * 32 + jj * 16 + lr;
                const float c = acc[i][jj][r] + bias[col];
                const float g = 0.5f * c * (1.0f + erff(c * 0.70710678118654752f));
                out[(size_t)row * N + col] = f2bf(g);
            }
}

// ---------------------------------------------------------------------------
// Flash attention — UNCHANGED from round-11 verified kernel (63.3 us).
// ---------------------------------------------------------------------------
__global__ __launch_bounds__(512)
void attn_mfma(const unsigned short* __restrict__ Qh,
               const unsigned short* __restrict__ Kh,
               const unsigned short* __restrict__ Vt,
               unsigned short* __restrict__ ctx)
{
    __shared__ unsigned short Ks[2][64 * 64];
    __shared__ unsigned short Vs[2][64 * 64];
    __shared__ unsigned short Ps[8][16 * 64];

    const int tid = threadIdx.x;
    const int w = tid >> 6, l = tid & 63;
    const int lr = l & 15, lg = l >> 4;

    const int p = blockIdx.x + blockIdx.y * 16;
    const int id = (p & 7) * 64 + (p >> 3);
    const int q0 = (id & 15) << 7;
    const int bh = id >> 4;

    const unsigned short* Qb = Qh + (size_t)bh * 131072;
    const char* Kb = (const char*)(Kh + (size_t)bh * 131072);
    const char* Vb = (const char*)(Vt + (size_t)bh * 131072);

    short8 qf[2];
    #pragma unroll
    for (int c = 0; c < 2; ++c)
        qf[c] = *(const short8*)(Qb + (size_t)(q0 + w * 16 + lr) * 64 + c * 32 + lg * 8);

    float mrow = -1e30f;
    float lrow = 0.f;
    f32x4 accO[4] = {};

    auto STAGE = [&](int bf, int kt) {
        const int row = tid >> 3, u = tid & 7;
        const int su = u ^ (row & 7);
        GLD_LDS16(Kb + (size_t)(kt + row) * 128 + su * 16,
                  (char*)&Ks[bf][0] + (w * 64) * 16);
        GLD_LDS16(Vb + (size_t)row * 4096 + (size_t)kt * 2 + su * 16,
                  (char*)&Vs[bf][0] + (w * 64) * 16);
    };

    STAGE(0, 0);
    __syncthreads();

    int cur = 0;
    for (int t = 0; t < 32; ++t) {
        if (t < 31) STAGE(cur ^ 1, (t + 1) * 64);

        const char* Kbuf = (const char*)&Ks[cur][0];
        const char* Vbuf = (const char*)&Vs[cur][0];

        f32x4 sf[4] = {};
        __builtin_amdgcn_s_setprio(1);
        #pragma unroll
        for (int n = 0; n < 4; ++n) {
            const int krow = n * 16 + lr;
            const short8 kf0 = *(const short8*)(Kbuf + krow * 128 + ((0 * 4 + lg) ^ (lr & 7)) * 16);
            const short8 kf1 = *(const short8*)(Kbuf + krow * 128 + ((1 * 4 + lg) ^ (lr & 7)) * 16);
            sf[n] = MFMA16(kf0, qf[0], sf[n]);
            sf[n] = MFMA16(kf1, qf[1], sf[n]);
        }
        __builtin_amdgcn_s_setprio(0);

        short8 vf[4][2];
        #pragma unroll
        for (int n = 0; n < 4; ++n) {
            const int drow = n * 16 + lr;
            vf[n][0] = *(const short8*)(Vbuf + drow * 128 + ((0 * 4 + lg) ^ (lr & 7)) * 16);
            vf[n][1] = *(const short8*)(Vbuf + drow * 128 + ((1 * 4 + lg) ^ (lr & 7)) * 16);
        }

        float a = fmaxf(fmaxf(fmaxf(sf[0][0], sf[0][1]), fmaxf(sf[0][2], sf[0][3])),
                        fmaxf(fmaxf(sf[1][0], sf[1][1]), fmaxf(sf[1][2], sf[1][3])));
        float b2 = fmaxf(fmaxf(fmaxf(sf[2][0], sf[2][1]), fmaxf(sf[2][2], sf[2][3])),
                         fmaxf(fmaxf(sf[3][0], sf[3][1]), fmaxf(sf[3][2], sf[3][3])));
        float r2 = fmaxf(a, b2);
        r2 = fmaxf(r2, __shfl_xor(r2, 16));
        r2 = fmaxf(r2, __shfl_xor(r2, 32));
        const bool need = (r2 > mrow + DEFER_THR);
        if (__any(need)) {
            const float mnew = fmaxf(mrow, r2);
            const float rsc = ex2(mrow - mnew);
            lrow *= rsc;
            mrow = mnew;
            #pragma unroll
            for (int r = 0; r < 4; ++r) {
                const float rr = __shfl(rsc, (l & 48) | (lg * 4 + r));
                #pragma unroll
                for (int n = 0; n < 4; ++n) accO[n][r] *= rr;
            }
        }
        {
            const float m = mrow;
            float ls = lrow;
            char* pbase = (char*)&Ps[w][0] + lr * 128;
            #pragma unroll
            for (int n = 0; n < 4; ++n) {
                const float p0 = ex2(sf[n][0] - m);
                const float p1 = ex2(sf[n][1] - m);
                const float p2 = ex2(sf[n][2] - m);
                const float p3 = ex2(sf[n][3] - m);
                ls += (p0 + p1) + (p2 + p3);
                uint2 pk;
                pk.x = pk_bf16(p0, p1);
                pk.y = pk_bf16(p2, p3);
                *(uint2*)(pbase + (((n * 2 + (lg >> 1)) ^ (lr & 7)) * 16) + (lg & 1) * 8) = pk;
            }
            lrow = ls;
        }

        asm volatile("" ::: "memory");

        short8 pf[2];
        {
            const char* pb = (const char*)&Ps[w][0] + lr * 128;
            #pragma unroll
            for (int c = 0; c < 2; ++c) {
                union { uint2 q2[2]; short8 s8; } cvt;
                const char* base = pb + (((c * 4 + lg) ^ (lr & 7)) * 16);
                cvt.q2[0] = *(const uint2*)(base);
                cvt.q2[1] = *(const uint2*)(base + 8);
                pf[c] = cvt.s8;
            }
        }

        __builtin_amdgcn_s_setprio(1);
        #pragma unroll
        for (int n = 0; n < 4; ++n) {
            accO[n] = MFMA16(pf[0], vf[n][0], accO[n]);
            accO[n] = MFMA16(pf[1], vf[n][1], accO[n]);
        }
        __builtin_amdgcn_s_setprio(0);

        __syncthreads();
        cur ^= 1;
    }

    const int b = bh >> 4, h = bh & 15;
    {
        float ls = lrow;
        ls += __shfl_xor(ls, 16);
        ls += __shfl_xor(ls, 32);
        const float inv = 1.0f / ls;
        #pragma unroll
        for (int r = 0; r < 4; ++r) {
            const float vr = __shfl(inv, (l & 48) | (lg * 4 + r));
            const int srow = q0 + w * 16 + lg * 4 + r;
            const size_t base = ((size_t)b * 2048 + srow) * 1024 + h * 64;
            #pragma unroll
            for (int n = 0; n < 4; ++n)
                ctx[base + n * 16 + lr] = f2bf(accO[n][r] * vr);
        }
    }
}

// ---------------------------------------------------------------------------
extern "C" void kernel_launch(void* const* d_in, const int* in_sizes, int n_in,
                              void* d_out, int out_size, void* d_ws, size_t ws_size,
                              hipStream_t stream) {
    const float* q   = (const float*)d_in[0];
    const float* k   = (const float*)d_in[1];
    const float* v   = (const float*)d_in[2];
    const float* Wq  = (const float*)d_in[3];
    const float* bq  = (const float*)d_in[4];
    const float* Wk  = (const float*)d_in[5];
    const float* bk  = (const float*)d_in[6];
    const float* Wv  = (const float*)d_in[7];
    const float* bv  = (const float*)d_in[8];
    const float* Wo  = (const float*)d_in[9];
    const float* bo  = (const float*)d_in[10];
    const float* Wad = (const float*)d_in[11];
    const float* bad = (const float*)d_in[12];
    const float* Wau = (const float*)d_in[13];
    const float* bau = (const float*)d_in[14];

    const int M = 4096, D = 1024, AD = 128;
    const size_t SZ = (size_t)M * D;

    char* p = (char*)d_ws;
    size_t off = 0;
    auto alloc = [&](size_t bytes) { void* r = p + off; off = (off + bytes + 255) & ~(size_t)255; return r; };
    unsigned short* Wqb  = (unsigned short*)alloc((size_t)D * D * 2);
    unsigned short* Wkb  = (unsigned short*)alloc((size_t)D * D * 2);
    unsigned short* Wvb  = (unsigned short*)alloc((size_t)D * D * 2);
    unsigned short* Wob  = (unsigned short*)alloc((size_t)D * D * 2);
    unsigned short* Wadb = (unsigned short*)alloc((size_t)AD * D * 2);
    unsigned short* Waub = (unsigned short*)alloc((size_t)D * AD * 2);
    unsigned short* Qh   = (unsigned short*)alloc(SZ * 2);   // [B,H,S,64]
    unsigned short* Kh   = (unsigned short*)alloc(SZ * 2);   // [B,H,S,64]
    unsigned short* Vt   = (unsigned short*)alloc(SZ * 2);   // [B,H,64,S]
    unsigned short* ctx  = (unsigned short*)alloc(SZ * 2);   // [M,D]
    float*          outp = (float*)alloc(SZ * 4);            // O-proj fp32
    unsigned short* outb = (unsigned short*)alloc(SZ * 2);   // O-proj bf16
    unsigned short* a1   = (unsigned short*)alloc((size_t)M * AD * 2);

    CvtJobs j;
    j.src[0] = Wq;  j.dst[0] = Wqb;  j.n[0] = D * D;   j.scale[0] = QSCALE;
    j.src[1] = Wk;  j.dst[1] = Wkb;  j.n[1] = D * D;   j.scale[1] = 1.f;
    j.src[2] = Wv;  j.dst[2] = Wvb;  j.n[2] = D * D;   j.scale[2] = 1.f;
    j.src[3] = Wo;  j.dst[3] = Wob;  j.n[3] = D * D;   j.scale[3] = 1.f;
    j.src[4] = Wad; j.dst[4] = Wadb; j.n[4] = AD * D;  j.scale[4] = 1.f;
    j.src[5] = Wau; j.dst[5] = Waub; j.n[5] = D * AD;  j.scale[5] = 1.f;
    long long total = 4LL * D * D + 2LL * AD * D;
    long long total4 = total / 4;
    convert_kernel<<<dim3((unsigned)((total4 + 255) / 256)), dim3(256), 0, stream>>>(j, total4);

    const dim3 blk(256);

    QKVArgs qa;
    qa.A[0] = q;   qa.A[1] = k;   qa.A[2] = v;          // fp32 direct
    qa.W[0] = Wqb; qa.W[1] = Wkb; qa.W[2] = Wvb;
    qa.bias[0] = bq; qa.bias[1] = bk; qa.bias[2] = bv;
    qa.bscale[0] = QSCALE; qa.bscale[1] = 1.f; qa.bscale[2] = 1.f;
    qa.out[0] = Qh; qa.out[1] = Kh; qa.out[2] = Vt;
    gemm_qkv<<<dim3(M / 128, D / 128, 3), blk, 0, stream>>>(qa, M, D, D);

    // 512 blocks (32 bh x 16 q-blocks of 128 rows), 512 threads / 8 waves each
    attn_mfma<<<dim3(16, 32), dim3(512), 0, stream>>>(Qh, Kh, Vt, ctx);

    gemm_bf16<2><<<dim3(M / 128, D / 128), blk, 0, stream>>>(ctx, Wob, bo, outp, outb, M, D, D);
    gemm64_gelu<<<dim3(M / 64, AD / 64), blk, 0, stream>>>(outb, Wadb, bad, a1, M, AD, D);
    gemm_bf16<4><<<dim3(M / 128, D / 128), blk, 0, stream>>>(a1, Waub, bau, d_out, outp, M, D, AD);
}

// Round 13
// 152.408 us; speedup vs baseline: 1.2532x; 1.0066x over previous
//
#include <hip/hip_runtime.h>
#include <hip/hip_bf16.h>
#include <math.h>

// B=2, S=2048, D=1024, H=16, HD=64, AD=128, M=B*S=4096
typedef __attribute__((ext_vector_type(8))) short short8;
typedef __attribute__((ext_vector_type(4))) float f32x4;

#define MFMA16(a,b,c) __builtin_amdgcn_mfma_f32_16x16x32_bf16((a),(b),(c),0,0,0)

__device__ __forceinline__ unsigned short f2bf(float f){
    union { __hip_bfloat16 b; unsigned short u; } cv;
    cv.b = __float2bfloat16(f);
    return cv.u;
}
__device__ __forceinline__ unsigned pk_bf16(float a, float b){
    unsigned r;
    asm("v_cvt_pk_bf16_f32 %0, %1, %2" : "=v"(r) : "v"(a), "v"(b));
    return r;
}
// 2^x via v_exp_f32 (gfx950 hardware exp2)
__device__ __forceinline__ float ex2(float x){
    return __builtin_amdgcn_exp2f(x);
}

#define GLD_LDS16(g, s) \
    __builtin_amdgcn_global_load_lds((const __attribute__((address_space(1))) void*)(g), \
                                     (__attribute__((address_space(3))) void*)(s), 16, 0, 0)

// 0.125 (1/sqrt(HD)) * log2(e) folded into Wq/bq -> softmax uses exp2
#define QSCALE 0.18033688011112042f
#define DEFER_THR 11.0f

// ---------------------------------------------------------------------------
// fp32 -> bf16 batched conversion (weights only: 6 tensors)
// ---------------------------------------------------------------------------
struct CvtJobs {
    const float* src[6];
    unsigned short* dst[6];
    float scale[6];
    int n[6];
};

__global__ __launch_bounds__(256)
void convert_kernel(CvtJobs j, long long total4) {
    long long i4 = (long long)blockIdx.x * blockDim.x + threadIdx.x;
    if (i4 >= total4) return;
    long long rem = i4 * 4;
    int job = 0;
    while (job < 6 && rem >= j.n[job]) { rem -= j.n[job]; ++job; }
    if (job >= 6) return;
    const float sc = j.scale[job];
    const float4 v = *(const float4*)(j.src[job] + rem);
    ushort4 o;
    o.x = f2bf(v.x * sc); o.y = f2bf(v.y * sc);
    o.z = f2bf(v.z * sc); o.w = f2bf(v.w * sc);
    *(ushort4*)(j.dst[job] + rem) = o;
}

// ---------------------------------------------------------------------------
// Fused QKV projection, double-buffered. A is fp32 in HBM, REG-STAGED:
// fp32 tile -> registers (loads issued at loop top, latency hidden under
// MFMA) -> cvt_pk to bf16 -> ds_write_b64 into a bf16 LDS tile before the
// barrier. LDS = 2 x (8KB A + 8KB B) = 32KB -> 3 blocks/CU. Frag-read path
// identical to the verified bf16 GEMM (0 bank conflicts).
// z=0,1 -> head layout [b,h,s,64]; z=2 -> transposed [b,h,hd,s] (V).
// ---------------------------------------------------------------------------
struct QKVArgs {
    const float* A[3];                 // fp32 activations (q,k,v)
    const unsigned short* W[3];        // bf16 weights
    const float* bias[3];
    float bscale[3];
    unsigned short* out[3];
};

__global__ __launch_bounds__(256)
void gemm_qkv(QKVArgs ar, int M, int N, int K)
{
    __shared__ unsigned short As[2][128 * 32];   // bf16 A tiles (2 x 8KB)
    __shared__ unsigned short Bs[2][128 * 32];   // bf16 W tiles (2 x 8KB)

    const int z = blockIdx.z;
    const float* A = ar.A[z];
    const unsigned short* W = ar.W[z];
    const int tid = threadIdx.x;
    const int w = tid >> 6, l = tid & 63;
    const int lr = l & 15, lg = l >> 4;
    const int wr = w >> 1, wc = w & 1;
    const int m0 = blockIdx.x * 128, n0 = blockIdx.y * 128;
    const int ru = lg ^ ((lr >> 1) & 3);

    // A-slot assignment: sid = c*256+tid, row = sid>>3, s = sid&7.
    // Thread loads fp32 chunk (4 floats = bf16 elems s*4..s*4+3) of its row.
    int arow[4], aslot[4];
    #pragma unroll
    for (int c = 0; c < 4; ++c) {
        const int sid = c * 256 + tid;
        arow[c] = sid >> 3;
        aslot[c] = sid & 7;
    }

    // load A fp32 chunks for k-step k0 into regs
    float4 areg[4];
    auto LOADA = [&](int k0) {
        #pragma unroll
        for (int c = 0; c < 4; ++c)
            areg[c] = *(const float4*)((const char*)A +
                        ((size_t)(m0 + arow[c]) * K + k0) * 4 + aslot[c] * 16);
    };
    // cvt + write regs into bf16 LDS buffer bf (write swizzle matches read:
    // logical chunk s>>1 -> phys (s>>1)^((row>>1)&3), half s&1)
    auto WRITEA = [&](int bf) {
        #pragma unroll
        for (int c = 0; c < 4; ++c) {
            uint2 pk;
            pk.x = pk_bf16(areg[c].x, areg[c].y);
            pk.y = pk_bf16(areg[c].z, areg[c].w);
            const int row = arow[c], s = aslot[c];
            *(uint2*)((char*)&As[bf][0] + row * 64 +
                      (((s >> 1) ^ ((row >> 1) & 3)) * 16) + (s & 1) * 8) = pk;
        }
    };
    auto STAGE_B = [&](int bf, int k0) {
        #pragma unroll
        for (int c = 0; c < 2; ++c) {
            const int cid = c * 256 + tid;
            const int row = cid >> 2, u = cid & 3;
            const int su = u ^ ((row >> 1) & 3);
            GLD_LDS16((const char*)W + ((size_t)(n0 + row) * K + k0) * 2 + su * 16,
                      (char*)&Bs[bf][0] + (c * 256 + w * 64) * 16);
        }
    };

    f32x4 acc[4][4] = {};
    LOADA(0);
    STAGE_B(0, 0);
    WRITEA(0);
    __syncthreads();
    int cur = 0;

    for (int k0 = 0; k0 < K; k0 += 32) {
        const bool more = (k0 + 32 < K);
        if (more) { LOADA(k0 + 32); STAGE_B(cur ^ 1, k0 + 32); }

        short8 af[4], bfr[4];
        #pragma unroll
        for (int i = 0; i < 4; ++i)
            af[i] = *(const short8*)((const char*)&As[cur][0] + (wr * 64 + i * 16 + lr) * 64 + ru * 16);
        #pragma unroll
        for (int jj = 0; jj < 4; ++jj)
            bfr[jj] = *(const short8*)((const char*)&Bs[cur][0] + (wc * 64 + jj * 16 + lr) * 64 + ru * 16);
        #pragma unroll
        for (int i = 0; i < 4; ++i)
            #pragma unroll
            for (int jj = 0; jj < 4; ++jj)
                acc[i][jj] = MFMA16(af[i], bfr[jj], acc[i][jj]);

        if (more) WRITEA(cur ^ 1);   // cvt off MFMA critical path, pre-barrier
        __syncthreads();
        cur ^= 1;
    }

    const float* bias = ar.bias[z];
    const float bsc = ar.bscale[z];
    unsigned short* out = ar.out[z];
    #pragma unroll
    for (int i = 0; i < 4; ++i)
        #pragma unroll
        for (int jj = 0; jj < 4; ++jj)
            #pragma unroll
            for (int r = 0; r < 4; ++r) {
                const int row = m0 + wr * 64 + i * 16 + lg * 4 + r;
                const int col = n0 + wc * 64 + jj * 16 + lr;
                const float c = acc[i][jj][r] + bias[col] * bsc;
                const int b = row >> 11, s = row & 2047, h = col >> 6, hd = col & 63;
                if (z < 2)
                    out[((((size_t)(b * 16 + h)) * 2048 + s) << 6) + hd] = f2bf(c);
                else
                    out[((((size_t)(b * 16 + h)) * 64 + hd) << 11) + s] = f2bf(c);
            }
}

// ---------------------------------------------------------------------------
// Generic 128x128 GEMM (bf16 A), double-buffered. MODE 2: fp32 out0 + bf16
// out1 (O-proj). MODE 4: + fp32 residual(out1) -> fp32 out0 (adapter up).
// ---------------------------------------------------------------------------
template<int MODE>
__global__ __launch_bounds__(256)
void gemm_bf16(const unsigned short* __restrict__ A,
               const unsigned short* __restrict__ Wt,
               const float* __restrict__ bias,
               void* __restrict__ out0,
               void* __restrict__ out1,
               int M, int N, int K)
{
    __shared__ unsigned short As[2][128 * 32];
    __shared__ unsigned short Bs[2][128 * 32];

    const int tid = threadIdx.x;
    const int w = tid >> 6, l = tid & 63;
    const int lr = l & 15, lg = l >> 4;
    const int wr = w >> 1, wc = w & 1;
    const int m0 = blockIdx.x * 128, n0 = blockIdx.y * 128;
    const int ru = lg ^ ((lr >> 1) & 3);

    auto STAGE = [&](int bf, int k0) {
        #pragma unroll
        for (int c = 0; c < 2; ++c) {
            const int cid = c * 256 + tid;
            const int row = cid >> 2, u = cid & 3;
            const int su = u ^ ((row >> 1) & 3);
            GLD_LDS16((const char*)A  + ((size_t)(m0 + row) * K + k0) * 2 + su * 16,
                      (char*)&As[bf][0] + (c * 256 + w * 64) * 16);
            GLD_LDS16((const char*)Wt + ((size_t)(n0 + row) * K + k0) * 2 + su * 16,
                      (char*)&Bs[bf][0] + (c * 256 + w * 64) * 16);
        }
    };

    f32x4 acc[4][4] = {};
    STAGE(0, 0);
    __syncthreads();
    int cur = 0;

    for (int k0 = 0; k0 < K; k0 += 32) {
        if (k0 + 32 < K) STAGE(cur ^ 1, k0 + 32);

        short8 af[4], bfr[4];
        #pragma unroll
        for (int i = 0; i < 4; ++i)
            af[i] = *(const short8*)((const char*)&As[cur][0] + (wr * 64 + i * 16 + lr) * 64 + ru * 16);
        #pragma unroll
        for (int jj = 0; jj < 4; ++jj)
            bfr[jj] = *(const short8*)((const char*)&Bs[cur][0] + (wc * 64 + jj * 16 + lr) * 64 + ru * 16);
        #pragma unroll
        for (int i = 0; i < 4; ++i)
            #pragma unroll
            for (int jj = 0; jj < 4; ++jj)
                acc[i][jj] = MFMA16(af[i], bfr[jj], acc[i][jj]);

        __syncthreads();
        cur ^= 1;
    }

    #pragma unroll
    for (int i = 0; i < 4; ++i)
        #pragma unroll
        for (int jj = 0; jj < 4; ++jj)
            #pragma unroll
            for (int r = 0; r < 4; ++r) {
                const int row = m0 + wr * 64 + i * 16 + lg * 4 + r;
                const int col = n0 + wc * 64 + jj * 16 + lr;
                const float c = acc[i][jj][r] + bias[col];
                if (MODE == 2) {
                    ((float*)out0)[(size_t)row * N + col] = c;
                    ((unsigned short*)out1)[(size_t)row * N + col] = f2bf(c);
                } else {
                    ((float*)out0)[(size_t)row * N + col] =
                        c + ((const float*)out1)[(size_t)row * N + col];
                }
            }
}

// ---------------------------------------------------------------------------
// 64x64-tile GEMM + exact GELU (adapter down, N=128), double-buffered.
// ---------------------------------------------------------------------------
__global__ __launch_bounds__(256)
void gemm64_gelu(const unsigned short* __restrict__ A,
                 const unsigned short* __restrict__ Wt,
                 const float* __restrict__ bias,
                 unsigned short* __restrict__ out,
                 int M, int N, int K)
{
    __shared__ unsigned short As[2][64 * 32];
    __shared__ unsigned short Bs[2][64 * 32];

    const int tid = threadIdx.x;
    const int w = tid >> 6, l = tid & 63;
    const int lr = l & 15, lg = l >> 4;
    const int wr = w >> 1, wc = w & 1;
    const int m0 = blockIdx.x * 64, n0 = blockIdx.y * 64;

    auto STAGE = [&](int bf, int k0) {
        const int row = tid >> 2, ch = tid & 3;
        GLD_LDS16(A  + (size_t)(m0 + row) * K + k0 + ch * 8, &As[bf][0] + (w * 64) * 8);
        GLD_LDS16(Wt + (size_t)(n0 + row) * K + k0 + ch * 8, &Bs[bf][0] + (w * 64) * 8);
    };

    f32x4 acc[2][2] = {};
    STAGE(0, 0);
    __syncthreads();
    int cur = 0;

    for (int k0 = 0; k0 < K; k0 += 32) {
        if (k0 + 32 < K) STAGE(cur ^ 1, k0 + 32);

        short8 af[2], bfr[2];
        #pragma unroll
        for (int i = 0; i < 2; ++i)
            af[i] = *(const short8*)(&As[cur][0] + ((wr * 32 + i * 16 + lr) * 32 + lg * 8));
        #pragma unroll
        for (int jj = 0; jj < 2; ++jj)
            bfr[jj] = *(const short8*)(&Bs[cur][0] + ((wc * 32 + jj * 16 + lr) * 32 + lg * 8));
        #pragma unroll
        for (int i = 0; i < 2; ++i)
            #pragma unroll
            for (int jj = 0; jj < 2; ++jj)
                acc[i][jj] = MFMA16(af[i], bfr[jj], acc[i][jj]);

        __syncthreads();
        cur ^= 1;
    }

    #pragma unroll
    for (int i = 0; i < 2; ++i)
        #pragma unroll
        for (int jj = 0; jj < 2; ++jj)
            #pragma unroll
            for (int r = 0; r < 4; ++r) {
                const int row = m0 + wr * 32 + i * 16 + lg * 4 + r;
                const int col = n0 + wc * 32 + jj * 16 + lr;
                const float c = acc[i][jj][r] + bias[col];
                const float g = 0.5f * c * (1.0f + erff(c * 0.70710678118654752f));
                out[(size_t)row * N + col] = f2bf(g);
            }
}

// ---------------------------------------------------------------------------
// Flash attention — UNCHANGED verified kernel (63.3 us).
// ---------------------------------------------------------------------------
__global__ __launch_bounds__(512)
void attn_mfma(const unsigned short* __restrict__ Qh,
               const unsigned short* __restrict__ Kh,
               const unsigned short* __restrict__ Vt,
               unsigned short* __restrict__ ctx)
{
    __shared__ unsigned short Ks[2][64 * 64];
    __shared__ unsigned short Vs[2][64 * 64];
    __shared__ unsigned short Ps[8][16 * 64];

    const int tid = threadIdx.x;
    const int w = tid >> 6, l = tid & 63;
    const int lr = l & 15, lg = l >> 4;

    const int p = blockIdx.x + blockIdx.y * 16;
    const int id = (p & 7) * 64 + (p >> 3);
    const int q0 = (id & 15) << 7;
    const int bh = id >> 4;

    const unsigned short* Qb = Qh + (size_t)bh * 131072;
    const char* Kb = (const char*)(Kh + (size_t)bh * 131072);
    const char* Vb = (const char*)(Vt + (size_t)bh * 131072);

    short8 qf[2];
    #pragma unroll
    for (int c = 0; c < 2; ++c)
        qf[c] = *(const short8*)(Qb + (size_t)(q0 + w * 16 + lr) * 64 + c * 32 + lg * 8);

    float mrow = -1e30f;
    float lrow = 0.f;
    f32x4 accO[4] = {};

    auto STAGE = [&](int bf, int kt) {
        const int row = tid >> 3, u = tid & 7;
        const int su = u ^ (row & 7);
        GLD_LDS16(Kb + (size_t)(kt + row) * 128 + su * 16,
                  (char*)&Ks[bf][0] + (w * 64) * 16);
        GLD_LDS16(Vb + (size_t)row * 4096 + (size_t)kt * 2 + su * 16,
                  (char*)&Vs[bf][0] + (w * 64) * 16);
    };

    STAGE(0, 0);
    __syncthreads();

    int cur = 0;
    for (int t = 0; t < 32; ++t) {
        if (t < 31) STAGE(cur ^ 1, (t + 1) * 64);

        const char* Kbuf = (const char*)&Ks[cur][0];
        const char* Vbuf = (const char*)&Vs[cur][0];

        f32x4 sf[4] = {};
        __builtin_amdgcn_s_setprio(1);
        #pragma unroll
        for (int n = 0; n < 4; ++n) {
            const int krow = n * 16 + lr;
            const short8 kf0 = *(const short8*)(Kbuf + krow * 128 + ((0 * 4 + lg) ^ (lr & 7)) * 16);
            const short8 kf1 = *(const short8*)(Kbuf + krow * 128 + ((1 * 4 + lg) ^ (lr & 7)) * 16);
            sf[n] = MFMA16(kf0, qf[0], sf[n]);
            sf[n] = MFMA16(kf1, qf[1], sf[n]);
        }
        __builtin_amdgcn_s_setprio(0);

        short8 vf[4][2];
        #pragma unroll
        for (int n = 0; n < 4; ++n) {
            const int drow = n * 16 + lr;
            vf[n][0] = *(const short8*)(Vbuf + drow * 128 + ((0 * 4 + lg) ^ (lr & 7)) * 16);
            vf[n][1] = *(const short8*)(Vbuf + drow * 128 + ((1 * 4 + lg) ^ (lr & 7)) * 16);
        }

        float a = fmaxf(fmaxf(fmaxf(sf[0][0], sf[0][1]), fmaxf(sf[0][2], sf[0][3])),
                        fmaxf(fmaxf(sf[1][0], sf[1][1]), fmaxf(sf[1][2], sf[1][3])));
        float b2 = fmaxf(fmaxf(fmaxf(sf[2][0], sf[2][1]), fmaxf(sf[2][2], sf[2][3])),
                         fmaxf(fmaxf(sf[3][0], sf[3][1]), fmaxf(sf[3][2], sf[3][3])));
        float r2 = fmaxf(a, b2);
        r2 = fmaxf(r2, __shfl_xor(r2, 16));
        r2 = fmaxf(r2, __shfl_xor(r2, 32));
        const bool need = (r2 > mrow + DEFER_THR);
        if (__any(need)) {
            const float mnew = fmaxf(mrow, r2);
            const float rsc = ex2(mrow - mnew);
            lrow *= rsc;
            mrow = mnew;
            #pragma unroll
            for (int r = 0; r < 4; ++r) {
                const float rr = __shfl(rsc, (l & 48) | (lg * 4 + r));
                #pragma unroll
                for (int n = 0; n < 4; ++n) accO[n][r] *= rr;
            }
        }
        {
            const float m = mrow;
            float ls = lrow;
            char* pbase = (char*)&Ps[w][0] + lr * 128;
            #pragma unroll
            for (int n = 0; n < 4; ++n) {
                const float p0 = ex2(sf[n][0] - m);
                const float p1 = ex2(sf[n][1] - m);
                const float p2 = ex2(sf[n][2] - m);
                const float p3 = ex2(sf[n][3] - m);
                ls += (p0 + p1) + (p2 + p3);
                uint2 pk;
                pk.x = pk_bf16(p0, p1);
                pk.y = pk_bf16(p2, p3);
                *(uint2*)(pbase + (((n * 2 + (lg >> 1)) ^ (lr & 7)) * 16) + (lg & 1) * 8) = pk;
            }
            lrow = ls;
        }

        asm volatile("" ::: "memory");

        short8 pf[2];
        {
            const char* pb = (const char*)&Ps[w][0] + lr * 128;
            #pragma unroll
            for (int c = 0; c < 2; ++c) {
                union { uint2 q2[2]; short8 s8; } cvt;
                const char* base = pb + (((c * 4 + lg) ^ (lr & 7)) * 16);
                cvt.q2[0] = *(const uint2*)(base);
                cvt.q2[1] = *(const uint2*)(base + 8);
                pf[c] = cvt.s8;
            }
        }

        __builtin_amdgcn_s_setprio(1);
        #pragma unroll
        for (int n = 0; n < 4; ++n) {
            accO[n] = MFMA16(pf[0], vf[n][0], accO[n]);
            accO[n] = MFMA16(pf[1], vf[n][1], accO[n]);
        }
        __builtin_amdgcn_s_setprio(0);

        __syncthreads();
        cur ^= 1;
    }

    const int b = bh >> 4, h = bh & 15;
    {
        float ls = lrow;
        ls += __shfl_xor(ls, 16);
        ls += __shfl_xor(ls, 32);
        const float inv = 1.0f / ls;
        #pragma unroll
        for (int r = 0; r < 4; ++r) {
            const float vr = __shfl(inv, (l & 48) | (lg * 4 + r));
            const int srow = q0 + w * 16 + lg * 4 + r;
            const size_t base = ((size_t)b * 2048 + srow) * 1024 + h * 64;
            #pragma unroll
            for (int n = 0; n < 4; ++n)
                ctx[base + n * 16 + lr] = f2bf(accO[n][r] * vr);
        }
    }
}

// ---------------------------------------------------------------------------
extern "C" void kernel_launch(void* const* d_in, const int* in_sizes, int n_in,
                              void* d_out, int out_size, void* d_ws, size_t ws_size,
                              hipStream_t stream) {
    const float* q   = (const float*)d_in[0];
    const float* k   = (const float*)d_in[1];
    const float* v   = (const float*)d_in[2];
    const float* Wq  = (const float*)d_in[3];
    const float* bq  = (const float*)d_in[4];
    const float* Wk  = (const float*)d_in[5];
    const float* bk  = (const float*)d_in[6];
    const float* Wv  = (const float*)d_in[7];
    const float* bv  = (const float*)d_in[8];
    const float* Wo  = (const float*)d_in[9];
    const float* bo  = (const float*)d_in[10];
    const float* Wad = (const float*)d_in[11];
    const float* bad = (const float*)d_in[12];
    const float* Wau = (const float*)d_in[13];
    const float* bau = (const float*)d_in[14];

    const int M = 4096, D = 1024, AD = 128;
    const size_t SZ = (size_t)M * D;

    char* p = (char*)d_ws;
    size_t off = 0;
    auto alloc = [&](size_t bytes) { void* r = p + off; off = (off + bytes + 255) & ~(size_t)255; return r; };
    unsigned short* Wqb  = (unsigned short*)alloc((size_t)D * D * 2);
    unsigned short* Wkb  = (unsigned short*)alloc((size_t)D * D * 2);
    unsigned short* Wvb  = (unsigned short*)alloc((size_t)D * D * 2);
    unsigned short* Wob  = (unsigned short*)alloc((size_t)D * D * 2);
    unsigned short* Wadb = (unsigned short*)alloc((size_t)AD * D * 2);
    unsigned short* Waub = (unsigned short*)alloc((size_t)D * AD * 2);
    unsigned short* Qh   = (unsigned short*)alloc(SZ * 2);   // [B,H,S,64]
    unsigned short* Kh   = (unsigned short*)alloc(SZ * 2);   // [B,H,S,64]
    unsigned short* Vt   = (unsigned short*)alloc(SZ * 2);   // [B,H,64,S]
    unsigned short* ctx  = (unsigned short*)alloc(SZ * 2);   // [M,D]
    float*          outp = (float*)alloc(SZ * 4);            // O-proj fp32
    unsigned short* outb = (unsigned short*)alloc(SZ * 2);   // O-proj bf16
    unsigned short* a1   = (unsigned short*)alloc((size_t)M * AD * 2);

    CvtJobs j;
    j.src[0] = Wq;  j.dst[0] = Wqb;  j.n[0] = D * D;   j.scale[0] = QSCALE;
    j.src[1] = Wk;  j.dst[1] = Wkb;  j.n[1] = D * D;   j.scale[1] = 1.f;
    j.src[2] = Wv;  j.dst[2] = Wvb;  j.n[2] = D * D;   j.scale[2] = 1.f;
    j.src[3] = Wo;  j.dst[3] = Wob;  j.n[3] = D * D;   j.scale[3] = 1.f;
    j.src[4] = Wad; j.dst[4] = Wadb; j.n[4] = AD * D;  j.scale[4] = 1.f;
    j.src[5] = Wau; j.dst[5] = Waub; j.n[5] = D * AD;  j.scale[5] = 1.f;
    long long total = 4LL * D * D + 2LL * AD * D;
    long long total4 = total / 4;
    convert_kernel<<<dim3((unsigned)((total4 + 255) / 256)), dim3(256), 0, stream>>>(j, total4);

    const dim3 blk(256);

    QKVArgs qa;
    qa.A[0] = q;   qa.A[1] = k;   qa.A[2] = v;          // fp32 direct
    qa.W[0] = Wqb; qa.W[1] = Wkb; qa.W[2] = Wvb;
    qa.bias[0] = bq; qa.bias[1] = bk; qa.bias[2] = bv;
    qa.bscale[0] = QSCALE; qa.bscale[1] = 1.f; qa.bscale[2] = 1.f;
    qa.out[0] = Qh; qa.out[1] = Kh; qa.out[2] = Vt;
    gemm_qkv<<<dim3(M / 128, D / 128, 3), blk, 0, stream>>>(qa, M, D, D);

    // 512 blocks (32 bh x 16 q-blocks of 128 rows), 512 threads / 8 waves each
    attn_mfma<<<dim3(16, 32), dim3(512), 0, stream>>>(Qh, Kh, Vt, ctx);

    gemm_bf16<2><<<dim3(M / 128, D / 128), blk, 0, stream>>>(ctx, Wob, bo, outp, outb, M, D, D);
    gemm64_gelu<<<dim3(M / 64, AD / 64), blk, 0, stream>>>(outb, Wadb, bad, a1, M, AD, D);
    gemm_bf16<4><<<dim3(M / 128, D / 128), blk, 0, stream>>>(a1, Waub, bau, d_out, outp, M, D, AD);
}